// Round 2
// baseline (53.274 us; speedup 1.0000x reference)
//
#include <hip/hip_runtime.h>
#include <math.h>

#define NCH    30      // 20 classes + 2 conf + 2*4 box
#define NCLS   20
#define NPRED  1470    // 7*7*30
#define NLAB   100     // 20*5
#define IPB    4       // images per block (wave per image)
#define THREADS 256

__global__ __launch_bounds__(THREADS) void yolo_loss_fused(
    const float* __restrict__ predicts,    // [B,7,7,30]
    const float* __restrict__ labels,      // [B,20,5]
    const int*   __restrict__ objects_num, // [B]
    float*        __restrict__ partial,    // [nblocks] in ws
    unsigned int* __restrict__ counter,    // in ws, memset to 0 each call
    float*        __restrict__ out,        // d_out[0]
    int B, int nblocks)
{
    const int tid  = threadIdx.x;
    const int wave = tid >> 6;
    const int lane = tid & 63;
    const int g    = blockIdx.x;
    const int b    = g * IPB + wave;

    __shared__ __align__(16) float sP[IPB * NPRED];   // 23520 B
    __shared__ __align__(16) float sL[IPB * NLAB];    // 1600 B
    __shared__ float  S2[IPB * 49];
    __shared__ float  wsum[IPB];
    __shared__ double sd[IPB];
    __shared__ int    lastFlag;

    // ---- stage 4 images of predicts (1470 float4) + labels (100 float4) ----
    {
        const float4* src = (const float4*)(predicts + (size_t)g * (IPB * NPRED));
        float4* dst = (float4*)sP;
        #pragma unroll
        for (int i = tid; i < (IPB * NPRED) / 4; i += THREADS) dst[i] = src[i];
        const float4* lsrc = (const float4*)(labels + (size_t)g * (IPB * NLAB));
        float4* ldst = (float4*)sL;
        if (tid < (IPB * NLAB) / 4) ldst[tid] = lsrc[tid];
    }
    __syncthreads();

    const float* iP  = sP + wave * NPRED;
    const float* iL  = sL + wave * NLAB;
    float*       S2w = S2 + wave * 49;

    // ---- per-cell class-square sums + total conf-square (per image) ----
    float c2 = 0.f;
    if (lane < 49) {
        const float* cp = iP + lane * NCH;
        float s = 0.f;
        #pragma unroll
        for (int c = 0; c < NCLS; ++c) s += cp[c] * cp[c];
        S2w[lane] = s;
        c2 = cp[20] * cp[20] + cp[21] * cp[21];
    }
    #pragma unroll
    for (int off = 32; off; off >>= 1) c2 += __shfl_xor(c2, off, 64);
    __syncthreads();

    const int nobj = objects_num[b];
    float loss = 0.f;

    if (lane < 20 && lane < nobj) {
        const float GS = 64.f, IMG = 448.f;
        const float* lb = iL + lane * 5;
        const float x = lb[0], y = lb[1], w = lb[2], h = lb[3];
        const int cls = (int)lb[4];

        const int cx = (int)floorf(x / GS);
        const int cy = (int)floorf(y / GS);
        const float* cell = iP + (cy * 7 + cx) * NCH;

        const float tx0 = x - w * 0.5f, ty0 = y - h * 0.5f;
        const float tx1 = x + w * 0.5f, ty1 = y + h * 0.5f;
        const float sq2 = (tx1 - tx0) * (ty1 - ty0);

        float iou[2], pc[2], px[2], py[2], pw[2], ph[2];
        #pragma unroll
        for (int p = 0; p < 2; ++p) {
            const float* bp = cell + NCLS + 2 + 4 * p;   // channels 22..29
            const float bx = bp[0] * GS + GS * (float)cx;
            const float by = bp[1] * GS + GS * (float)cy;
            const float bw = bp[2] * IMG;
            const float bh = bp[3] * IMG;
            px[p] = bx; py[p] = by; pw[p] = bw; ph[p] = bh;
            const float ax0 = bx - bw * 0.5f, ay0 = by - bh * 0.5f;
            const float ax1 = bx + bw * 0.5f, ay1 = by + bh * 0.5f;
            const float lux = fmaxf(ax0, tx0), luy = fmaxf(ay0, ty0);
            const float rdx = fminf(ax1, tx1), rdy = fminf(ay1, ty1);
            const float iw = fmaxf(rdx - lux, 0.f), ih = fmaxf(rdy - luy, 0.f);
            const float ia = iw * ih;
            const float sq1 = (ax1 - ax0) * (ay1 - ay0);
            iou[p] = ia / (sq1 + sq2 - ia + 1e-6f);
            pc[p]  = cell[NCLS + p];
        }

        const float miou = fmaxf(iou[0], iou[1]);
        const float sqw = sqrtf(fabsf(w)), sqh = sqrtf(fabsf(h));

        float obj = 0.f, coord = 0.f, isumc2 = 0.f;
        #pragma unroll
        for (int p = 0; p < 2; ++p) {
            if (iou[p] >= miou) {          // ties -> both, matches reference >=
                const float d = pc[p] - iou[p];
                obj    += d * d;
                isumc2 += pc[p] * pc[p];
                const float dx = (px[p] - x) / GS;
                const float dy = (py[p] - y) / GS;
                const float psw = sqrtf(fminf(fmaxf(pw[p], 0.f), IMG));
                const float psh = sqrtf(fminf(fmaxf(ph[p], 0.f), IMG));
                const float dw = psw - sqw, dh = psh - sqh;
                coord += dx * dx + dy * dy + (dw * dw + dh * dh) / IMG;
            }
        }

        const float object_loss   = 0.5f  * obj;           // OBJECT_SCALE * _l2
        const float noobject_loss = 0.25f * (c2 - isumc2);  // 0.5 * 0.5
        const float coord_loss    = 2.5f  * coord;          // 5 * 0.5

        // class loss over object_mask rectangle; CLASS_SCALE * 0.5 = 1
        const int x0 = (int)fmaxf(0.f, floorf(tx0 / GS));
        const int x1 = (int)fminf(7.f, ceilf (tx1 / GS));
        const int y0 = (int)fmaxf(0.f, floorf(ty0 / GS));
        const int y1 = (int)fminf(7.f, ceilf (ty1 / GS));
        float cl = 0.f;
        for (int iy = y0; iy < y1; ++iy)
            for (int ix = x0; ix < x1; ++ix) {
                const int ci = iy * 7 + ix;
                cl += S2w[ci] - 2.f * iP[ci * NCH + cls] + 1.f;
            }

        loss = object_loss + noobject_loss + coord_loss + cl;
    }

    // ---- wave reduce, then block partial ----
    #pragma unroll
    for (int off = 32; off; off >>= 1) loss += __shfl_xor(loss, off, 64);
    if (lane == 0) wsum[wave] = loss;
    __syncthreads();

    if (tid == 0) {
        const float p = wsum[0] + wsum[1] + wsum[2] + wsum[3];
        __hip_atomic_store(&partial[g], p, __ATOMIC_RELEASE, __HIP_MEMORY_SCOPE_AGENT);
        __threadfence();
        const unsigned int old =
            __hip_atomic_fetch_add(counter, 1u, __ATOMIC_ACQ_REL, __HIP_MEMORY_SCOPE_AGENT);
        lastFlag = (old + 1u == (unsigned int)nblocks);
    }
    __syncthreads();

    // ---- last block does the deterministic final reduction ----
    if (lastFlag) {
        __threadfence();
        double s = 0.0;
        for (int i = tid; i < nblocks; i += THREADS)
            s += (double)__hip_atomic_load(&partial[i], __ATOMIC_RELAXED,
                                           __HIP_MEMORY_SCOPE_AGENT);
        #pragma unroll
        for (int off = 32; off; off >>= 1) s += __shfl_xor(s, off, 64);
        if (lane == 0) sd[wave] = s;
        __syncthreads();
        if (tid == 0)
            out[0] = (float)((sd[0] + sd[1] + sd[2] + sd[3]) / (double)B);
    }
}

extern "C" void kernel_launch(void* const* d_in, const int* in_sizes, int n_in,
                              void* d_out, int out_size, void* d_ws, size_t ws_size,
                              hipStream_t stream) {
    const float* predicts = (const float*)d_in[0];
    const float* labels   = (const float*)d_in[1];
    const int*   objnum   = (const int*)d_in[2];
    const int B = in_sizes[0] / NPRED;   // 4096
    const int nblocks = B / IPB;         // 1024

    float*        partials = (float*)d_ws;
    unsigned int* counter  = (unsigned int*)((char*)d_ws + (size_t)nblocks * sizeof(float));

    hipMemsetAsync(counter, 0, sizeof(unsigned int), stream);
    yolo_loss_fused<<<nblocks, THREADS, 0, stream>>>(
        predicts, labels, objnum, partials, counter, (float*)d_out, B, nblocks);
}

// Round 3
// 21.091 us; speedup vs baseline: 2.5259x; 2.5259x over previous
//
#include <hip/hip_runtime.h>
#include <math.h>

#define NCH    30      // 20 classes + 2 conf + 2*4 box
#define NCLS   20
#define NPRED  1470    // 7*7*30
#define NLAB   100     // 20*5
#define IPB    8       // images per block (one wave per image)
#define THREADS (IPB * 64)

__global__ __launch_bounds__(THREADS) void yolo_loss_fused(
    const float* __restrict__ predicts,    // [B,7,7,30]
    const float* __restrict__ labels,      // [B,20,5]
    const int*   __restrict__ objects_num, // [B]
    float*       out,                      // d_out[0], zeroed by memset each call
    float inv_B)
{
    const int tid  = threadIdx.x;
    const int wave = tid >> 6;
    const int lane = tid & 63;
    const int g    = blockIdx.x;
    const int b    = g * IPB + wave;

    __shared__ __align__(16) float sP[IPB * NPRED];   // 47040 B
    __shared__ __align__(16) float sL[IPB * NLAB];    // 3200 B
    __shared__ float S2[IPB * 49];
    __shared__ float wsum[IPB];

    // ---- stage IPB images of predicts + labels (float4-coalesced) ----
    {
        const float4* src = (const float4*)(predicts + (size_t)g * (IPB * NPRED));
        float4* dst = (float4*)sP;
        #pragma unroll
        for (int i = tid; i < (IPB * NPRED) / 4; i += THREADS) dst[i] = src[i];
        const float4* lsrc = (const float4*)(labels + (size_t)g * (IPB * NLAB));
        float4* ldst = (float4*)sL;
        if (tid < (IPB * NLAB) / 4) ldst[tid] = lsrc[tid];
    }
    __syncthreads();

    const float* iP  = sP + wave * NPRED;
    const float* iL  = sL + wave * NLAB;
    float*       S2w = S2 + wave * 49;

    // ---- per-cell class-square sums + total conf-square (per image) ----
    float c2 = 0.f;
    if (lane < 49) {
        const float* cp = iP + lane * NCH;
        float s = 0.f;
        #pragma unroll
        for (int c = 0; c < NCLS; ++c) s += cp[c] * cp[c];
        S2w[lane] = s;
        c2 = cp[20] * cp[20] + cp[21] * cp[21];
    }
    #pragma unroll
    for (int off = 32; off; off >>= 1) c2 += __shfl_xor(c2, off, 64);
    __syncthreads();

    const int nobj = objects_num[b];
    float loss = 0.f;

    if (lane < 20 && lane < nobj) {
        const float GS = 64.f, IMG = 448.f;
        const float* lb = iL + lane * 5;
        const float x = lb[0], y = lb[1], w = lb[2], h = lb[3];
        const int cls = (int)lb[4];

        const int cx = (int)floorf(x / GS);
        const int cy = (int)floorf(y / GS);
        const float* cell = iP + (cy * 7 + cx) * NCH;

        const float tx0 = x - w * 0.5f, ty0 = y - h * 0.5f;
        const float tx1 = x + w * 0.5f, ty1 = y + h * 0.5f;
        const float sq2 = (tx1 - tx0) * (ty1 - ty0);

        float iou[2], pc[2], px[2], py[2], pw[2], ph[2];
        #pragma unroll
        for (int p = 0; p < 2; ++p) {
            const float* bp = cell + NCLS + 2 + 4 * p;   // channels 22..29
            const float bx = bp[0] * GS + GS * (float)cx;
            const float by = bp[1] * GS + GS * (float)cy;
            const float bw = bp[2] * IMG;
            const float bh = bp[3] * IMG;
            px[p] = bx; py[p] = by; pw[p] = bw; ph[p] = bh;
            const float ax0 = bx - bw * 0.5f, ay0 = by - bh * 0.5f;
            const float ax1 = bx + bw * 0.5f, ay1 = by + bh * 0.5f;
            const float lux = fmaxf(ax0, tx0), luy = fmaxf(ay0, ty0);
            const float rdx = fminf(ax1, tx1), rdy = fminf(ay1, ty1);
            const float iw = fmaxf(rdx - lux, 0.f), ih = fmaxf(rdy - luy, 0.f);
            const float ia = iw * ih;
            const float sq1 = (ax1 - ax0) * (ay1 - ay0);
            iou[p] = ia / (sq1 + sq2 - ia + 1e-6f);
            pc[p]  = cell[NCLS + p];
        }

        const float miou = fmaxf(iou[0], iou[1]);
        const float sqw = sqrtf(fabsf(w)), sqh = sqrtf(fabsf(h));

        float obj = 0.f, coord = 0.f, isumc2 = 0.f;
        #pragma unroll
        for (int p = 0; p < 2; ++p) {
            if (iou[p] >= miou) {          // ties -> both, matches reference >=
                const float d = pc[p] - iou[p];
                obj    += d * d;
                isumc2 += pc[p] * pc[p];
                const float dx = (px[p] - x) / GS;
                const float dy = (py[p] - y) / GS;
                const float psw = sqrtf(fminf(fmaxf(pw[p], 0.f), IMG));
                const float psh = sqrtf(fminf(fmaxf(ph[p], 0.f), IMG));
                const float dw = psw - sqw, dh = psh - sqh;
                coord += dx * dx + dy * dy + (dw * dw + dh * dh) / IMG;
            }
        }

        const float object_loss   = 0.5f  * obj;           // OBJECT_SCALE * _l2
        const float noobject_loss = 0.25f * (c2 - isumc2);  // 0.5 * 0.5
        const float coord_loss    = 2.5f  * coord;          // 5 * 0.5

        // class loss over object_mask rectangle; CLASS_SCALE * 0.5 = 1
        const int x0 = (int)fmaxf(0.f, floorf(tx0 / GS));
        const int x1 = (int)fminf(7.f, ceilf (tx1 / GS));
        const int y0 = (int)fmaxf(0.f, floorf(ty0 / GS));
        const int y1 = (int)fminf(7.f, ceilf (ty1 / GS));
        float cl = 0.f;
        for (int iy = y0; iy < y1; ++iy)
            for (int ix = x0; ix < x1; ++ix) {
                const int ci = iy * 7 + ix;
                cl += S2w[ci] - 2.f * iP[ci * NCH + cls] + 1.f;
            }

        loss = object_loss + noobject_loss + coord_loss + cl;
    }

    // ---- wave reduce, block combine, one relaxed atomic per block ----
    #pragma unroll
    for (int off = 32; off; off >>= 1) loss += __shfl_xor(loss, off, 64);
    if (lane == 0) wsum[wave] = loss;
    __syncthreads();

    if (tid == 0) {
        float p = 0.f;
        #pragma unroll
        for (int i = 0; i < IPB; ++i) p += wsum[i];
        atomicAdd(out, p * inv_B);   // plain device-scope RMW: no fences, no L2 flush
    }
}

extern "C" void kernel_launch(void* const* d_in, const int* in_sizes, int n_in,
                              void* d_out, int out_size, void* d_ws, size_t ws_size,
                              hipStream_t stream) {
    const float* predicts = (const float*)d_in[0];
    const float* labels   = (const float*)d_in[1];
    const int*   objnum   = (const int*)d_in[2];
    const int B = in_sizes[0] / NPRED;   // 4096
    const int nblocks = B / IPB;         // 512

    hipMemsetAsync(d_out, 0, sizeof(float), stream);
    yolo_loss_fused<<<nblocks, THREADS, 0, stream>>>(
        predicts, labels, objnum, (float*)d_out, 1.0f / (float)B);
}

// Round 4
// 15.892 us; speedup vs baseline: 3.3521x; 1.3271x over previous
//
#include <hip/hip_runtime.h>
#include <math.h>

#define NCH    30      // 20 classes + 2 conf + 2*4 box
#define NCLS   20
#define NPRED  1470    // 7*7*30
#define WPB    4       // waves per block = images per block
#define THREADS (WPB * 64)

// Main kernel: one wave per image, wave-private LDS, no barriers, no atomics.
__global__ __launch_bounds__(THREADS) void yolo_main(
    const float* __restrict__ predicts,    // [B,7,7,30]
    const float* __restrict__ labels,      // [B,20,5]
    const int*   __restrict__ objects_num, // [B]
    float*       __restrict__ partial)     // [B] in ws
{
    const int tid  = threadIdx.x;
    const int wave = tid >> 6;
    const int lane = tid & 63;
    const int b    = blockIdx.x * WPB + wave;

    __shared__ __align__(16) float sP[WPB][NPRED];  // 23520 B, wave-private slices
    __shared__ float S2s[WPB][49];                  // wave-private

    float* iP = sP[wave];

    // ---- stage this wave's image (735 float2, contiguous, coalesced) ----
    {
        const float2* src = (const float2*)(predicts + (size_t)b * NPRED);
        float2* dst = (float2*)iP;
        #pragma unroll
        for (int i = lane; i < NPRED / 2; i += 64) dst[i] = src[i];
    }
    // no __syncthreads: same-wave LDS write->read is ordered by lgkmcnt

    // ---- per-cell class-square sums + total conf-square ----
    float c2 = 0.f;
    if (lane < 49) {
        const float* cp = iP + lane * NCH;
        float s = 0.f;
        #pragma unroll
        for (int c = 0; c < NCLS; ++c) s += cp[c] * cp[c];
        S2s[wave][lane] = s;
        c2 = cp[20] * cp[20] + cp[21] * cp[21];
    }
    #pragma unroll
    for (int off = 32; off; off >>= 1) c2 += __shfl_xor(c2, off, 64);

    const int nobj = objects_num[b];
    float loss = 0.f;

    if (lane < 20 && lane < nobj) {
        const float GS = 64.f, IMG = 448.f;
        const float* lb = labels + (size_t)b * 100 + lane * 5;  // direct global (L2)
        const float x = lb[0], y = lb[1], w = lb[2], h = lb[3];
        const int cls = (int)lb[4];

        const int cx = (int)floorf(x / GS);
        const int cy = (int)floorf(y / GS);
        const float* cell = iP + (cy * 7 + cx) * NCH;

        const float tx0 = x - w * 0.5f, ty0 = y - h * 0.5f;
        const float tx1 = x + w * 0.5f, ty1 = y + h * 0.5f;
        const float sq2 = (tx1 - tx0) * (ty1 - ty0);

        float iou[2], pc[2], px[2], py[2], pw[2], ph[2];
        #pragma unroll
        for (int p = 0; p < 2; ++p) {
            const float* bp = cell + NCLS + 2 + 4 * p;   // channels 22..29
            const float bx = bp[0] * GS + GS * (float)cx;
            const float by = bp[1] * GS + GS * (float)cy;
            const float bw = bp[2] * IMG;
            const float bh = bp[3] * IMG;
            px[p] = bx; py[p] = by; pw[p] = bw; ph[p] = bh;
            const float ax0 = bx - bw * 0.5f, ay0 = by - bh * 0.5f;
            const float ax1 = bx + bw * 0.5f, ay1 = by + bh * 0.5f;
            const float lux = fmaxf(ax0, tx0), luy = fmaxf(ay0, ty0);
            const float rdx = fminf(ax1, tx1), rdy = fminf(ay1, ty1);
            const float iw = fmaxf(rdx - lux, 0.f), ih = fmaxf(rdy - luy, 0.f);
            const float ia = iw * ih;
            const float sq1 = (ax1 - ax0) * (ay1 - ay0);
            iou[p] = ia / (sq1 + sq2 - ia + 1e-6f);
            pc[p]  = cell[NCLS + p];
        }

        const float miou = fmaxf(iou[0], iou[1]);
        const float sqw = sqrtf(fabsf(w)), sqh = sqrtf(fabsf(h));

        float obj = 0.f, coord = 0.f, isumc2 = 0.f;
        #pragma unroll
        for (int p = 0; p < 2; ++p) {
            if (iou[p] >= miou) {          // ties -> both, matches reference >=
                const float d = pc[p] - iou[p];
                obj    += d * d;
                isumc2 += pc[p] * pc[p];
                const float dx = (px[p] - x) / GS;
                const float dy = (py[p] - y) / GS;
                const float psw = sqrtf(fminf(fmaxf(pw[p], 0.f), IMG));
                const float psh = sqrtf(fminf(fmaxf(ph[p], 0.f), IMG));
                const float dw = psw - sqw, dh = psh - sqh;
                coord += dx * dx + dy * dy + (dw * dw + dh * dh) / IMG;
            }
        }

        const float object_loss   = 0.5f  * obj;           // OBJECT_SCALE * _l2
        const float noobject_loss = 0.25f * (c2 - isumc2);  // 0.5 * 0.5
        const float coord_loss    = 2.5f  * coord;          // 5 * 0.5

        // class loss over object_mask rectangle; CLASS_SCALE * 0.5 = 1
        const int x0 = (int)fmaxf(0.f, floorf(tx0 / GS));
        const int x1 = (int)fminf(7.f, ceilf (tx1 / GS));
        const int y0 = (int)fmaxf(0.f, floorf(ty0 / GS));
        const int y1 = (int)fminf(7.f, ceilf (ty1 / GS));
        float cl = 0.f;
        for (int iy = y0; iy < y1; ++iy)
            for (int ix = x0; ix < x1; ++ix) {
                const int ci = iy * 7 + ix;
                cl += S2s[wave][ci] - 2.f * iP[ci * NCH + cls] + 1.f;
            }

        loss = object_loss + noobject_loss + coord_loss + cl;
    }

    // ---- wave reduce, plain store (dispatch boundary provides coherence) ----
    #pragma unroll
    for (int off = 32; off; off >>= 1) loss += __shfl_xor(loss, off, 64);
    if (lane == 0) partial[b] = loss;
}

// Deterministic final reduction of B partials, / B.
__global__ __launch_bounds__(256) void yolo_reduce(
    const float* __restrict__ partial, float* __restrict__ out, int B)
{
    const int tid = threadIdx.x;
    const float4* p4 = (const float4*)partial;
    double s = 0.0;
    for (int i = tid; i < B / 4; i += 256) {
        const float4 v = p4[i];
        s += (double)v.x + (double)v.y + (double)v.z + (double)v.w;
    }
    #pragma unroll
    for (int off = 32; off; off >>= 1) s += __shfl_xor(s, off, 64);
    __shared__ double sd[4];
    if ((tid & 63) == 0) sd[tid >> 6] = s;
    __syncthreads();
    if (tid == 0)
        out[0] = (float)((sd[0] + sd[1] + sd[2] + sd[3]) / (double)B);
}

extern "C" void kernel_launch(void* const* d_in, const int* in_sizes, int n_in,
                              void* d_out, int out_size, void* d_ws, size_t ws_size,
                              hipStream_t stream) {
    const float* predicts = (const float*)d_in[0];
    const float* labels   = (const float*)d_in[1];
    const int*   objnum   = (const int*)d_in[2];
    const int B = in_sizes[0] / NPRED;   // 4096
    const int nblocks = B / WPB;         // 1024

    float* partials = (float*)d_ws;      // B floats = 16 KB scratch

    yolo_main<<<nblocks, THREADS, 0, stream>>>(predicts, labels, objnum, partials);
    yolo_reduce<<<1, 256, 0, stream>>>(partials, (float*)d_out, B);
}

// Round 5
// 15.418 us; speedup vs baseline: 3.4554x; 1.0308x over previous
//
#include <hip/hip_runtime.h>
#include <math.h>

#define NCH    30      // 20 classes + 2 conf + 2*4 box
#define NCLS   20
#define NPRED  1470    // 7*7*30
#define WPB    4       // waves per block = images per block
#define THREADS (WPB * 64)

// Main kernel: one wave per image, wave-private LDS staging, one barrier at end.
__global__ __launch_bounds__(THREADS) void yolo_main(
    const float* __restrict__ predicts,    // [B,7,7,30]
    const float* __restrict__ labels,      // [B,20,5]
    const int*   __restrict__ objects_num, // [B]
    float*       __restrict__ partial)     // [nblocks] in ws
{
    const int tid  = threadIdx.x;
    const int wave = tid >> 6;
    const int lane = tid & 63;
    const int b    = blockIdx.x * WPB + wave;

    __shared__ __align__(16) float sP[WPB][NPRED];  // 23520 B, wave-private slices
    __shared__ float S2s[WPB][49];
    __shared__ float wsum[WPB];

    float* iP = sP[wave];

    // ---- stage this wave's image (735 float2, contiguous, coalesced) ----
    {
        const float2* src = (const float2*)(predicts + (size_t)b * NPRED);
        float2* dst = (float2*)iP;
        #pragma unroll
        for (int i = lane; i < NPRED / 2; i += 64) dst[i] = src[i];
    }
    // no barrier needed here: same-wave LDS write->read ordered by lgkmcnt

    // ---- per-cell class-square sums + total conf-square ----
    float c2 = 0.f;
    if (lane < 49) {
        const float* cp = iP + lane * NCH;
        float s = 0.f;
        #pragma unroll
        for (int c = 0; c < NCLS; ++c) s += cp[c] * cp[c];
        S2s[wave][lane] = s;
        c2 = cp[20] * cp[20] + cp[21] * cp[21];
    }
    #pragma unroll
    for (int off = 32; off; off >>= 1) c2 += __shfl_xor(c2, off, 64);

    const int nobj = objects_num[b];
    float loss = 0.f;

    if (lane < 20 && lane < nobj) {
        const float GS = 64.f, IMG = 448.f;
        const float* lb = labels + (size_t)b * 100 + lane * 5;  // direct global (L2/L3)
        const float x = lb[0], y = lb[1], w = lb[2], h = lb[3];
        const int cls = (int)lb[4];

        const int cx = (int)floorf(x / GS);
        const int cy = (int)floorf(y / GS);
        const float* cell = iP + (cy * 7 + cx) * NCH;

        const float tx0 = x - w * 0.5f, ty0 = y - h * 0.5f;
        const float tx1 = x + w * 0.5f, ty1 = y + h * 0.5f;
        const float sq2 = (tx1 - tx0) * (ty1 - ty0);

        float iou[2], pc[2], px[2], py[2], pw[2], ph[2];
        #pragma unroll
        for (int p = 0; p < 2; ++p) {
            const float* bp = cell + NCLS + 2 + 4 * p;   // channels 22..29
            const float bx = bp[0] * GS + GS * (float)cx;
            const float by = bp[1] * GS + GS * (float)cy;
            const float bw = bp[2] * IMG;
            const float bh = bp[3] * IMG;
            px[p] = bx; py[p] = by; pw[p] = bw; ph[p] = bh;
            const float ax0 = bx - bw * 0.5f, ay0 = by - bh * 0.5f;
            const float ax1 = bx + bw * 0.5f, ay1 = by + bh * 0.5f;
            const float lux = fmaxf(ax0, tx0), luy = fmaxf(ay0, ty0);
            const float rdx = fminf(ax1, tx1), rdy = fminf(ay1, ty1);
            const float iw = fmaxf(rdx - lux, 0.f), ih = fmaxf(rdy - luy, 0.f);
            const float ia = iw * ih;
            const float sq1 = (ax1 - ax0) * (ay1 - ay0);
            iou[p] = ia / (sq1 + sq2 - ia + 1e-6f);
            pc[p]  = cell[NCLS + p];
        }

        const float miou = fmaxf(iou[0], iou[1]);
        const float sqw = sqrtf(fabsf(w)), sqh = sqrtf(fabsf(h));

        float obj = 0.f, coord = 0.f, isumc2 = 0.f;
        #pragma unroll
        for (int p = 0; p < 2; ++p) {
            if (iou[p] >= miou) {          // ties -> both, matches reference >=
                const float d = pc[p] - iou[p];
                obj    += d * d;
                isumc2 += pc[p] * pc[p];
                const float dx = (px[p] - x) / GS;
                const float dy = (py[p] - y) / GS;
                const float psw = sqrtf(fminf(fmaxf(pw[p], 0.f), IMG));
                const float psh = sqrtf(fminf(fmaxf(ph[p], 0.f), IMG));
                const float dw = psw - sqw, dh = psh - sqh;
                coord += dx * dx + dy * dy + (dw * dw + dh * dh) / IMG;
            }
        }

        const float object_loss   = 0.5f  * obj;            // OBJECT_SCALE * _l2
        const float noobject_loss = 0.25f * (c2 - isumc2);  // 0.5 * 0.5
        const float coord_loss    = 2.5f  * coord;           // 5 * 0.5

        // class loss over object_mask rectangle; CLASS_SCALE * 0.5 = 1
        const int x0 = (int)fmaxf(0.f, floorf(tx0 / GS));
        const int x1 = (int)fminf(7.f, ceilf (tx1 / GS));
        const int y0 = (int)fmaxf(0.f, floorf(ty0 / GS));
        const int y1 = (int)fminf(7.f, ceilf (ty1 / GS));
        float cl = 0.f;
        for (int iy = y0; iy < y1; ++iy)
            for (int ix = x0; ix < x1; ++ix) {
                const int ci = iy * 7 + ix;
                cl += S2s[wave][ci] - 2.f * iP[ci * NCH + cls] + 1.f;
            }

        loss = object_loss + noobject_loss + coord_loss + cl;
    }

    // ---- wave reduce -> block partial (one barrier), plain store ----
    #pragma unroll
    for (int off = 32; off; off >>= 1) loss += __shfl_xor(loss, off, 64);
    if (lane == 0) wsum[wave] = loss;
    __syncthreads();
    if (tid == 0)
        partial[blockIdx.x] = wsum[0] + wsum[1] + wsum[2] + wsum[3];
}

// Deterministic final reduction: 1024 block partials -> out, one float4/thread.
__global__ __launch_bounds__(256) void yolo_reduce(
    const float* __restrict__ partial, float* __restrict__ out,
    int nblocks, int B)
{
    const int tid = threadIdx.x;
    const float4* p4 = (const float4*)partial;
    double s = 0.0;
    if (tid < nblocks / 4) {                 // 256 threads x float4 = 1024 floats
        const float4 v = p4[tid];
        s = (double)v.x + (double)v.y + (double)v.z + (double)v.w;
    }
    #pragma unroll
    for (int off = 32; off; off >>= 1) s += __shfl_xor(s, off, 64);
    __shared__ double sd[4];
    if ((tid & 63) == 0) sd[tid >> 6] = s;
    __syncthreads();
    if (tid == 0)
        out[0] = (float)((sd[0] + sd[1] + sd[2] + sd[3]) / (double)B);
}

extern "C" void kernel_launch(void* const* d_in, const int* in_sizes, int n_in,
                              void* d_out, int out_size, void* d_ws, size_t ws_size,
                              hipStream_t stream) {
    const float* predicts = (const float*)d_in[0];
    const float* labels   = (const float*)d_in[1];
    const int*   objnum   = (const int*)d_in[2];
    const int B = in_sizes[0] / NPRED;   // 4096
    const int nblocks = B / WPB;         // 1024

    float* partials = (float*)d_ws;      // nblocks floats = 4 KB scratch

    yolo_main<<<nblocks, THREADS, 0, stream>>>(predicts, labels, objnum, partials);
    yolo_reduce<<<1, 256, 0, stream>>>(partials, (float*)d_out, nblocks, B);
}

// Round 6
// 13.468 us; speedup vs baseline: 3.9555x; 1.1447x over previous
//
#include <hip/hip_runtime.h>
#include <math.h>

#define NCH    30      // 20 classes + 2 conf + 2*4 box
#define NCLS   20
#define NPRED  1470    // 7*7*30
#define WPB    8       // waves per block = images per block
#define THREADS (WPB * 64)

// Main kernel: 8 images/block, block-cooperative float4 staging, wave per image.
__global__ __launch_bounds__(THREADS) void yolo_main(
    const float* __restrict__ predicts,    // [B,7,7,30]
    const float* __restrict__ labels,      // [B,20,5]
    const int*   __restrict__ objects_num, // [B]
    float*       __restrict__ partial)     // [nblocks] in ws
{
    const int tid  = threadIdx.x;
    const int wave = tid >> 6;
    const int lane = tid & 63;
    const int b    = blockIdx.x * WPB + wave;

    __shared__ __align__(16) float sP[WPB][NPRED];  // 47040 B
    __shared__ float S2s[WPB][49];
    __shared__ float wsum[WPB];

    // ---- hoist tiny per-lane global reads (latency hides under staging) ----
    const int nobj = objects_num[b];
    float lx = 0.f, ly = 0.f, lw = 0.f, lh = 0.f; int cls = 0;
    const bool active = (lane < 20) && (lane < nobj);
    if (active) {
        const float* lb = labels + (size_t)b * 100 + lane * 5;
        lx = lb[0]; ly = lb[1]; lw = lb[2]; lh = lb[3]; cls = (int)lb[4];
    }

    // ---- block-cooperative float4 staging: 8 images = 2940 float4 ----
    {
        const float4* src = (const float4*)(predicts + (size_t)blockIdx.x * (WPB * NPRED));
        float4* dst = (float4*)&sP[0][0];
        #pragma unroll
        for (int i = tid; i < (WPB * NPRED) / 4; i += THREADS) dst[i] = src[i];
    }
    __syncthreads();

    const float* iP = sP[wave];

    // ---- per-cell class-square sums + total conf-square ----
    float c2 = 0.f;
    if (lane < 49) {
        const float* cp = iP + lane * NCH;
        float s = 0.f;
        #pragma unroll
        for (int c = 0; c < NCLS; ++c) s += cp[c] * cp[c];
        S2s[wave][lane] = s;
        c2 = cp[20] * cp[20] + cp[21] * cp[21];
    }
    #pragma unroll
    for (int off = 32; off; off >>= 1) c2 += __shfl_xor(c2, off, 64);

    float loss = 0.f;

    if (active) {
        const float GS = 64.f, IMG = 448.f;
        const float x = lx, y = ly, w = lw, h = lh;

        const int cx = (int)floorf(x / GS);
        const int cy = (int)floorf(y / GS);
        const float* cell = iP + (cy * 7 + cx) * NCH;

        const float tx0 = x - w * 0.5f, ty0 = y - h * 0.5f;
        const float tx1 = x + w * 0.5f, ty1 = y + h * 0.5f;
        const float sq2 = (tx1 - tx0) * (ty1 - ty0);

        float iou[2], pc[2], px[2], py[2], pw[2], ph[2];
        #pragma unroll
        for (int p = 0; p < 2; ++p) {
            const float* bp = cell + NCLS + 2 + 4 * p;   // channels 22..29
            const float bx = bp[0] * GS + GS * (float)cx;
            const float by = bp[1] * GS + GS * (float)cy;
            const float bw = bp[2] * IMG;
            const float bh = bp[3] * IMG;
            px[p] = bx; py[p] = by; pw[p] = bw; ph[p] = bh;
            const float ax0 = bx - bw * 0.5f, ay0 = by - bh * 0.5f;
            const float ax1 = bx + bw * 0.5f, ay1 = by + bh * 0.5f;
            const float lux = fmaxf(ax0, tx0), luy = fmaxf(ay0, ty0);
            const float rdx = fminf(ax1, tx1), rdy = fminf(ay1, ty1);
            const float iw = fmaxf(rdx - lux, 0.f), ih = fmaxf(rdy - luy, 0.f);
            const float ia = iw * ih;
            const float sq1 = (ax1 - ax0) * (ay1 - ay0);
            iou[p] = ia / (sq1 + sq2 - ia + 1e-6f);
            pc[p]  = cell[NCLS + p];
        }

        const float miou = fmaxf(iou[0], iou[1]);
        const float sqw = sqrtf(fabsf(w)), sqh = sqrtf(fabsf(h));

        float obj = 0.f, coord = 0.f, isumc2 = 0.f;
        #pragma unroll
        for (int p = 0; p < 2; ++p) {
            if (iou[p] >= miou) {          // ties -> both, matches reference >=
                const float d = pc[p] - iou[p];
                obj    += d * d;
                isumc2 += pc[p] * pc[p];
                const float dx = (px[p] - x) / GS;
                const float dy = (py[p] - y) / GS;
                const float psw = sqrtf(fminf(fmaxf(pw[p], 0.f), IMG));
                const float psh = sqrtf(fminf(fmaxf(ph[p], 0.f), IMG));
                const float dw = psw - sqw, dh = psh - sqh;
                coord += dx * dx + dy * dy + (dw * dw + dh * dh) / IMG;
            }
        }

        const float object_loss   = 0.5f  * obj;            // OBJECT_SCALE * _l2
        const float noobject_loss = 0.25f * (c2 - isumc2);  // 0.5 * 0.5
        const float coord_loss    = 2.5f  * coord;           // 5 * 0.5

        // class loss over object_mask rectangle; CLASS_SCALE * 0.5 = 1
        const int x0 = (int)fmaxf(0.f, floorf(tx0 / GS));
        const int x1 = (int)fminf(7.f, ceilf (tx1 / GS));
        const int y0 = (int)fmaxf(0.f, floorf(ty0 / GS));
        const int y1 = (int)fminf(7.f, ceilf (ty1 / GS));
        float cl = 0.f;
        for (int iy = y0; iy < y1; ++iy)
            for (int ix = x0; ix < x1; ++ix) {
                const int ci = iy * 7 + ix;
                cl += S2s[wave][ci] - 2.f * iP[ci * NCH + cls] + 1.f;
            }

        loss = object_loss + noobject_loss + coord_loss + cl;
    }

    // ---- wave reduce -> block partial, plain store ----
    #pragma unroll
    for (int off = 32; off; off >>= 1) loss += __shfl_xor(loss, off, 64);
    if (lane == 0) wsum[wave] = loss;
    __syncthreads();
    if (tid == 0) {
        float p = 0.f;
        #pragma unroll
        for (int i = 0; i < WPB; ++i) p += wsum[i];
        partial[blockIdx.x] = p;
    }
}

// Deterministic final reduction: 512 block partials -> out, one float4/thread.
__global__ __launch_bounds__(256) void yolo_reduce(
    const float* __restrict__ partial, float* __restrict__ out,
    int nblocks, int B)
{
    const int tid = threadIdx.x;
    const float4* p4 = (const float4*)partial;
    double s = 0.0;
    if (tid < nblocks / 4) {                 // 128 threads x float4 = 512 floats
        const float4 v = p4[tid];
        s = (double)v.x + (double)v.y + (double)v.z + (double)v.w;
    }
    #pragma unroll
    for (int off = 32; off; off >>= 1) s += __shfl_xor(s, off, 64);
    __shared__ double sd[4];
    if ((tid & 63) == 0) sd[tid >> 6] = s;
    __syncthreads();
    if (tid == 0)
        out[0] = (float)((sd[0] + sd[1] + sd[2] + sd[3]) / (double)B);
}

extern "C" void kernel_launch(void* const* d_in, const int* in_sizes, int n_in,
                              void* d_out, int out_size, void* d_ws, size_t ws_size,
                              hipStream_t stream) {
    const float* predicts = (const float*)d_in[0];
    const float* labels   = (const float*)d_in[1];
    const int*   objnum   = (const int*)d_in[2];
    const int B = in_sizes[0] / NPRED;   // 4096
    const int nblocks = B / WPB;         // 512

    float* partials = (float*)d_ws;      // nblocks floats = 2 KB scratch

    yolo_main<<<nblocks, THREADS, 0, stream>>>(predicts, labels, objnum, partials);
    yolo_reduce<<<1, 256, 0, stream>>>(partials, (float*)d_out, nblocks, B);
}

// Round 7
// 13.316 us; speedup vs baseline: 4.0007x; 1.0114x over previous
//
#include <hip/hip_runtime.h>
#include <math.h>

#define NCH    30      // 20 classes + 2 conf + 2*4 box
#define NCLS   20
#define NPRED  1470    // 7*7*30
#define WPB    8       // waves per block = images per block
#define THREADS (WPB * 64)

// Main kernel: 8 images/block, block-cooperative float4 staging, wave per image.
__global__ __launch_bounds__(THREADS) void yolo_main(
    const float* __restrict__ predicts,    // [B,7,7,30]
    const float* __restrict__ labels,      // [B,20,5]
    const int*   __restrict__ objects_num, // [B]
    float*       __restrict__ partial)     // [nblocks] in ws
{
    const int tid  = threadIdx.x;
    const int wave = tid >> 6;
    const int lane = tid & 63;
    const int b    = blockIdx.x * WPB + wave;

    __shared__ __align__(16) float sP[WPB][NPRED];  // 47040 B
    __shared__ float S2s[WPB][49];
    __shared__ float wsum[WPB];

    // ---- hoist tiny per-lane global reads (latency hides under staging) ----
    const int nobj = objects_num[b];
    float lx = 0.f, ly = 0.f, lw = 0.f, lh = 0.f; int cls = 0;
    const bool active = (lane < 20) && (lane < nobj);
    if (active) {
        const float* lb = labels + (size_t)b * 100 + lane * 5;
        lx = lb[0]; ly = lb[1]; lw = lb[2]; lh = lb[3]; cls = (int)lb[4];
    }

    // ---- block-cooperative float4 staging: 8 images = 2940 float4 ----
    {
        const float4* src = (const float4*)(predicts + (size_t)blockIdx.x * (WPB * NPRED));
        float4* dst = (float4*)&sP[0][0];
        #pragma unroll
        for (int i = tid; i < (WPB * NPRED) / 4; i += THREADS) dst[i] = src[i];
    }
    __syncthreads();

    const float* iP = sP[wave];

    // ---- per-cell class-square sums + total conf-square ----
    float c2 = 0.f;
    if (lane < 49) {
        const float* cp = iP + lane * NCH;
        float s = 0.f;
        #pragma unroll
        for (int c = 0; c < NCLS; ++c) s += cp[c] * cp[c];
        S2s[wave][lane] = s;
        c2 = cp[20] * cp[20] + cp[21] * cp[21];
    }
    #pragma unroll
    for (int off = 32; off; off >>= 1) c2 += __shfl_xor(c2, off, 64);

    float loss = 0.f;

    if (active) {
        const float GS = 64.f, IMG = 448.f;
        const float x = lx, y = ly, w = lw, h = lh;

        const int cx = (int)floorf(x / GS);
        const int cy = (int)floorf(y / GS);
        const float* cell = iP + (cy * 7 + cx) * NCH;

        const float tx0 = x - w * 0.5f, ty0 = y - h * 0.5f;
        const float tx1 = x + w * 0.5f, ty1 = y + h * 0.5f;
        const float sq2 = (tx1 - tx0) * (ty1 - ty0);

        float iou[2], pc[2], px[2], py[2], pw[2], ph[2];
        #pragma unroll
        for (int p = 0; p < 2; ++p) {
            const float* bp = cell + NCLS + 2 + 4 * p;   // channels 22..29
            const float bx = bp[0] * GS + GS * (float)cx;
            const float by = bp[1] * GS + GS * (float)cy;
            const float bw = bp[2] * IMG;
            const float bh = bp[3] * IMG;
            px[p] = bx; py[p] = by; pw[p] = bw; ph[p] = bh;
            const float ax0 = bx - bw * 0.5f, ay0 = by - bh * 0.5f;
            const float ax1 = bx + bw * 0.5f, ay1 = by + bh * 0.5f;
            const float lux = fmaxf(ax0, tx0), luy = fmaxf(ay0, ty0);
            const float rdx = fminf(ax1, tx1), rdy = fminf(ay1, ty1);
            const float iw = fmaxf(rdx - lux, 0.f), ih = fmaxf(rdy - luy, 0.f);
            const float ia = iw * ih;
            const float sq1 = (ax1 - ax0) * (ay1 - ay0);
            iou[p] = ia / (sq1 + sq2 - ia + 1e-6f);
            pc[p]  = cell[NCLS + p];
        }

        const float miou = fmaxf(iou[0], iou[1]);
        const float sqw = sqrtf(fabsf(w)), sqh = sqrtf(fabsf(h));

        float obj = 0.f, coord = 0.f, isumc2 = 0.f;
        #pragma unroll
        for (int p = 0; p < 2; ++p) {
            if (iou[p] >= miou) {          // ties -> both, matches reference >=
                const float d = pc[p] - iou[p];
                obj    += d * d;
                isumc2 += pc[p] * pc[p];
                const float dx = (px[p] - x) / GS;
                const float dy = (py[p] - y) / GS;
                const float psw = sqrtf(fminf(fmaxf(pw[p], 0.f), IMG));
                const float psh = sqrtf(fminf(fmaxf(ph[p], 0.f), IMG));
                const float dw = psw - sqw, dh = psh - sqh;
                coord += dx * dx + dy * dy + (dw * dw + dh * dh) / IMG;
            }
        }

        const float object_loss   = 0.5f  * obj;            // OBJECT_SCALE * _l2
        const float noobject_loss = 0.25f * (c2 - isumc2);  // 0.5 * 0.5
        const float coord_loss    = 2.5f  * coord;           // 5 * 0.5

        // class loss over object_mask rectangle; CLASS_SCALE * 0.5 = 1
        const int x0 = (int)fmaxf(0.f, floorf(tx0 / GS));
        const int x1 = (int)fminf(7.f, ceilf (tx1 / GS));
        const int y0 = (int)fmaxf(0.f, floorf(ty0 / GS));
        const int y1 = (int)fminf(7.f, ceilf (ty1 / GS));
        float cl = 0.f;
        for (int iy = y0; iy < y1; ++iy)
            for (int ix = x0; ix < x1; ++ix) {
                const int ci = iy * 7 + ix;
                cl += S2s[wave][ci] - 2.f * iP[ci * NCH + cls] + 1.f;
            }

        loss = object_loss + noobject_loss + coord_loss + cl;
    }

    // ---- wave reduce -> block partial, plain store ----
    #pragma unroll
    for (int off = 32; off; off >>= 1) loss += __shfl_xor(loss, off, 64);
    if (lane == 0) wsum[wave] = loss;
    __syncthreads();
    if (tid == 0) {
        float p = 0.f;
        #pragma unroll
        for (int i = 0; i < WPB; ++i) p += wsum[i];
        partial[blockIdx.x] = p;
    }
}

// Single-wave deterministic final reduction: 512 partials, no LDS, no barriers.
__global__ __launch_bounds__(64) void yolo_reduce(
    const float* __restrict__ partial, float* __restrict__ out, int B)
{
    const int lane = threadIdx.x;      // 0..63
    const float4* p4 = (const float4*)partial;
    // two independent float4 loads per lane: 64*2*4 = 512 floats
    const float4 a = p4[lane];
    const float4 b = p4[lane + 64];
    double s = ((double)a.x + (double)a.y + (double)a.z + (double)a.w)
             + ((double)b.x + (double)b.y + (double)b.z + (double)b.w);
    #pragma unroll
    for (int off = 32; off; off >>= 1) s += __shfl_xor(s, off, 64);
    if (lane == 0) out[0] = (float)(s / (double)B);
}

extern "C" void kernel_launch(void* const* d_in, const int* in_sizes, int n_in,
                              void* d_out, int out_size, void* d_ws, size_t ws_size,
                              hipStream_t stream) {
    const float* predicts = (const float*)d_in[0];
    const float* labels   = (const float*)d_in[1];
    const int*   objnum   = (const int*)d_in[2];
    const int B = in_sizes[0] / NPRED;   // 4096
    const int nblocks = B / WPB;         // 512

    float* partials = (float*)d_ws;      // nblocks floats = 2 KB scratch

    yolo_main<<<nblocks, THREADS, 0, stream>>>(predicts, labels, objnum, partials);
    yolo_reduce<<<1, 64, 0, stream>>>(partials, (float*)d_out, B);
}